// Round 3
// baseline (37.436 us; speedup 1.0000x reference)
//
#include <hip/hip_runtime.h>

// Problem constants: b=4, f=6, n_slots=7, n_buffer=8, h=w=128, 3 channels.
constexpr int NB  = 8;
constexpr int NS  = 7;
constexpr int NCH = 3;
constexpr int HW  = 128 * 128;    // 16384
constexpr int BF  = 24;
constexpr int BLOCK = 256;
constexpr int CHUNKS = HW / BLOCK;               // 64 blocks per bf, 1 px/thread
constexpr float INV_HW = 1.0f / (float)HW;
constexpr float SCALE  = 20.0f / (4.0f * 6.0f * 7.0f * 8.0f);
constexpr float LOG_CLAMP = -100.0f;

__global__ __launch_bounds__(BLOCK)
void em_loss_kernel(const float* __restrict__ seg,
                    const float* __restrict__ masks,
                    const float* __restrict__ rec,
                    const float* __restrict__ rtgt,
                    const float* __restrict__ mvis,
                    const float* __restrict__ ai,
                    float* __restrict__ out) {
    const int bf    = blockIdx.x >> 6;           // / CHUNKS
    const int chunk = blockIdx.x & (CHUNKS - 1);
    const int tid   = threadIdx.x;
    const int hw    = chunk * BLOCK + tid;       // 1 px/thread

    __shared__ float ai_s[NS][NB];
    __shared__ float A_s[NB];
    if (tid < NS * NB)
        ((float*)ai_s)[tid] = ai[bf * NS * NB + tid];
    __syncthreads();
    if (tid < NB) {
        float a = 0.f;
        #pragma unroll
        for (int s = 0; s < NS; ++s) a += ai_s[s][tid];
        A_s[tid] = a;
    }
    __syncthreads();

    const float* segp = seg  + (size_t)bf * NB * HW        + hw;
    const float* mp   = masks + (size_t)bf * NS * HW       + hw;
    const float* rp   = rec  + (size_t)bf * NB * NCH * HW  + hw;
    const float* tp   = rtgt + (size_t)bf * NCH * HW       + hw;
    const float* vp   = mvis + (size_t)bf * NS * HW        + hw;

    // Issue all independent loads up front.
    float sv[NB];
    #pragma unroll
    for (int c = 0; c < NB; ++c) sv[c] = segp[c * HW];

    float t[NCH];
    #pragma unroll
    for (int ch = 0; ch < NCH; ++ch) t[ch] = tp[ch * HW];

    float mb[NS], vb[NS];
    #pragma unroll
    for (int s = 0; s < NS; ++s) {
        mb[s] = (mp[s * HW] > 0.5f) ? 1.f : 0.f;
        vb[s] = (vp[s * HW] > 0.5f) ? 1.f : 0.f;
    }

    float acc = 0.f;
    #pragma unroll
    for (int c = 0; c < NB; ++c) {
        float r0 = rp[(c * NCH + 0) * HW];
        float r1 = rp[(c * NCH + 1) * HW];
        float r2 = rp[(c * NCH + 2) * HW];
        float s  = sv[c];
        float lp = fmaxf(__logf(s), LOG_CLAMP);
        float l1 = fmaxf(__logf(1.0f - s), LOG_CLAMP);
        float d0 = r0 - t[0];
        float d1 = r1 - t[1];
        float d2 = r2 - t[2];
        float D  = d0 * d0 + d1 * d1 + d2 * d2;
        float U = 0.f, V = 0.f;
        #pragma unroll
        for (int s7 = 0; s7 < NS; ++s7) {
            float a = ai_s[s7][c];
            U = fmaf(mb[s7], a, U);
            V = fmaf(vb[s7], a, V);
        }
        acc += -(A_s[c] * l1 + U * (lp - l1)) * INV_HW + 0.1f * V * D;
    }

    // wave reduce then cross-wave via LDS, one atomic per block
    #pragma unroll
    for (int off = 32; off; off >>= 1) acc += __shfl_down(acc, off, 64);
    __shared__ float wsum[BLOCK / 64];
    const int wid  = tid >> 6;
    const int lane = tid & 63;
    if (lane == 0) wsum[wid] = acc;
    __syncthreads();
    if (tid == 0) {
        float a = wsum[0] + wsum[1] + wsum[2] + wsum[3];
        atomicAdd(out, a * SCALE);
    }
}

extern "C" void kernel_launch(void* const* d_in, const int* in_sizes, int n_in,
                              void* d_out, int out_size, void* d_ws, size_t ws_size,
                              hipStream_t stream) {
    const float* seg   = (const float*)d_in[0];  // (4,6,8,128,128)
    const float* masks = (const float*)d_in[1];  // (4,6,7,128,128)
    const float* rec   = (const float*)d_in[2];  // (4,6,8,3,128,128)
    const float* rtgt  = (const float*)d_in[3];  // (4,6,3,128,128)
    const float* mvis  = (const float*)d_in[4];  // (4,6,7,128,128)
    const float* ai    = (const float*)d_in[5];  // (4,6,7,8)
    float* out = (float*)d_out;

    hipMemsetAsync(out, 0, sizeof(float), stream);
    em_loss_kernel<<<BF * CHUNKS, BLOCK, 0, stream>>>(seg, masks, rec, rtgt, mvis, ai, out);
}

// Round 4
// 30.461 us; speedup vs baseline: 1.2290x; 1.2290x over previous
//
#include <hip/hip_runtime.h>

// b=4, f=6, n_slots=7, n_buffer=8, h=w=128, 3 channels. bf=24.
constexpr int NB  = 8;
constexpr int NS  = 7;
constexpr int NCH = 3;
constexpr int HW  = 128 * 128;    // 16384
constexpr int HW4 = HW / 4;       // 4096 float4 per plane
constexpr int BF  = 24;
constexpr int BLOCK = 256;
// Each block: 1024 px (256 thr x 4 px) x half of the buffer dim.
constexpr int PXCHUNKS = HW / (BLOCK * 4);       // 16
constexpr int BLOCKS_PER_BF = PXCHUNKS * 2;      // 32 (x2 c-halves)
constexpr float INV_HW = 1.0f / (float)HW;
constexpr float SCALE  = 20.0f / (4.0f * 6.0f * 7.0f * 8.0f);
constexpr float LOG_CLAMP = -100.0f;

__global__ __launch_bounds__(BLOCK)
void em_loss_kernel(const float* __restrict__ seg,
                    const float* __restrict__ masks,
                    const float* __restrict__ rec,
                    const float* __restrict__ rtgt,
                    const float* __restrict__ mvis,
                    const float* __restrict__ ai,
                    float* __restrict__ out) {
    const int bf    = blockIdx.x >> 5;           // / BLOCKS_PER_BF
    const int rem   = blockIdx.x & 31;
    const int half  = rem & 1;                   // c-half: 0 -> c=0..3, 1 -> c=4..7
    const int chunk = rem >> 1;                  // 0..15
    const int tid   = threadIdx.x;
    const int v4    = chunk * BLOCK + tid;       // float4 index in plane
    const int c0    = half * 4;

    __shared__ float ai_s[NS][NB];
    __shared__ float A_s[NB];
    if (tid < NS * NB)
        ((float*)ai_s)[tid] = ai[bf * NS * NB + tid];
    __syncthreads();
    if (tid < NB) {
        float a = 0.f;
        #pragma unroll
        for (int s = 0; s < NS; ++s) a += ai_s[s][tid];
        A_s[tid] = a;
    }
    __syncthreads();

    const float4* segp = (const float4*)(seg  + (size_t)bf * NB * HW)       + v4;
    const float4* mp   = (const float4*)(masks + (size_t)bf * NS * HW)      + v4;
    const float4* rp   = (const float4*)(rec  + (size_t)bf * NB * NCH * HW) + v4;
    const float4* tp   = (const float4*)(rtgt + (size_t)bf * NCH * HW)      + v4;
    const float4* vp   = (const float4*)(mvis + (size_t)bf * NS * HW)       + v4;

    // ---- Issue ALL 33 float4 loads up front; keep results live. ----
    float4 sv[4];                                // seg, c = c0..c0+3
    #pragma unroll
    for (int c4 = 0; c4 < 4; ++c4) sv[c4] = segp[(c0 + c4) * HW4];

    float4 rr[4][NCH];                           // rec
    #pragma unroll
    for (int c4 = 0; c4 < 4; ++c4)
        #pragma unroll
        for (int ch = 0; ch < NCH; ++ch)
            rr[c4][ch] = rp[((c0 + c4) * NCH + ch) * HW4];

    float4 mv[NS], vv[NS];                       // masks, masks_vis
    #pragma unroll
    for (int s = 0; s < NS; ++s) mv[s] = mp[s * HW4];
    #pragma unroll
    for (int s = 0; s < NS; ++s) vv[s] = vp[s * HW4];

    float4 tv[NCH];                              // rec_tgt
    #pragma unroll
    for (int ch = 0; ch < NCH; ++ch) tv[ch] = tp[ch * HW4];

    // ---- Compute ----
    // mask bits as 0/1 floats, c-independent
    float mb[NS][4], vb[NS][4];
    #pragma unroll
    for (int s = 0; s < NS; ++s) {
        const float* m4 = (const float*)&mv[s];
        const float* v4p = (const float*)&vv[s];
        #pragma unroll
        for (int j = 0; j < 4; ++j) {
            mb[s][j] = (m4[j] > 0.5f) ? 1.f : 0.f;
            vb[s][j] = (v4p[j] > 0.5f) ? 1.f : 0.f;
        }
    }

    float acc = 0.f;
    #pragma unroll
    for (int c4 = 0; c4 < 4; ++c4) {
        const int c = c0 + c4;
        const float Ac = A_s[c];
        const float* sp  = (const float*)&sv[c4];
        const float* r0p = (const float*)&rr[c4][0];
        const float* r1p = (const float*)&rr[c4][1];
        const float* r2p = (const float*)&rr[c4][2];
        const float* t0p = (const float*)&tv[0];
        const float* t1p = (const float*)&tv[1];
        const float* t2p = (const float*)&tv[2];
        #pragma unroll
        for (int j = 0; j < 4; ++j) {
            float s  = sp[j];
            float lp = fmaxf(__logf(s), LOG_CLAMP);
            float l1 = fmaxf(__logf(1.0f - s), LOG_CLAMP);
            float d0 = r0p[j] - t0p[j];
            float d1 = r1p[j] - t1p[j];
            float d2 = r2p[j] - t2p[j];
            float D  = d0 * d0 + d1 * d1 + d2 * d2;
            float U = 0.f, V = 0.f;
            #pragma unroll
            for (int s7 = 0; s7 < NS; ++s7) {
                float a = ai_s[s7][c];
                U = fmaf(mb[s7][j], a, U);
                V = fmaf(vb[s7][j], a, V);
            }
            acc += -(Ac * l1 + U * (lp - l1)) * INV_HW + 0.1f * V * D;
        }
    }

    // wave reduce, then cross-wave via LDS, one atomic per block
    #pragma unroll
    for (int off = 32; off; off >>= 1) acc += __shfl_down(acc, off, 64);
    __shared__ float wsum[BLOCK / 64];
    const int wid  = tid >> 6;
    const int lane = tid & 63;
    if (lane == 0) wsum[wid] = acc;
    __syncthreads();
    if (tid == 0) {
        float a = wsum[0] + wsum[1] + wsum[2] + wsum[3];
        atomicAdd(out, a * SCALE);
    }
}

extern "C" void kernel_launch(void* const* d_in, const int* in_sizes, int n_in,
                              void* d_out, int out_size, void* d_ws, size_t ws_size,
                              hipStream_t stream) {
    const float* seg   = (const float*)d_in[0];  // (4,6,8,128,128)
    const float* masks = (const float*)d_in[1];  // (4,6,7,128,128)
    const float* rec   = (const float*)d_in[2];  // (4,6,8,3,128,128)
    const float* rtgt  = (const float*)d_in[3];  // (4,6,3,128,128)
    const float* mvis  = (const float*)d_in[4];  // (4,6,7,128,128)
    const float* ai    = (const float*)d_in[5];  // (4,6,7,8)
    float* out = (float*)d_out;

    hipMemsetAsync(out, 0, sizeof(float), stream);
    em_loss_kernel<<<BF * BLOCKS_PER_BF, BLOCK, 0, stream>>>(seg, masks, rec, rtgt, mvis, ai, out);
}

// Round 5
// 25.660 us; speedup vs baseline: 1.4589x; 1.1871x over previous
//
#include <hip/hip_runtime.h>

// b=4, f=6, n_slots=7, n_buffer=8, h=w=128, 3 channels. bf=24.
constexpr int NB  = 8;
constexpr int NS  = 7;
constexpr int NCH = 3;
constexpr int HW  = 128 * 128;    // 16384
constexpr int HW4 = HW / 4;       // 4096 float4 per plane
constexpr int BF  = 24;
constexpr int BLOCK = 256;
constexpr int PXCHUNKS = HW / (BLOCK * 4);       // 16
constexpr int BLOCKS_PER_BF = PXCHUNKS * 2;      // 32 (x2 c-halves)
constexpr int NPART = BF * BLOCKS_PER_BF;        // 768 partials
constexpr float INV_HW = 1.0f / (float)HW;
constexpr float SCALE  = 20.0f / (4.0f * 6.0f * 7.0f * 8.0f);
constexpr float LOG_CLAMP = -100.0f;

__global__ __launch_bounds__(BLOCK, 3)
void em_loss_kernel(const float* __restrict__ seg,
                    const float* __restrict__ masks,
                    const float* __restrict__ rec,
                    const float* __restrict__ rtgt,
                    const float* __restrict__ mvis,
                    const float* __restrict__ ai,
                    float* __restrict__ part) {
    const int bf    = blockIdx.x >> 5;           // / BLOCKS_PER_BF
    const int rem   = blockIdx.x & 31;
    const int half  = rem & 1;                   // c-half: 0 -> c=0..3, 1 -> c=4..7
    const int chunk = rem >> 1;                  // 0..15
    const int tid   = threadIdx.x;
    const int v4    = chunk * BLOCK + tid;       // float4 index in plane
    const int c0    = half * 4;

    __shared__ float ai_s[NS][NB];
    __shared__ float A_s[NB];
    if (tid < NS * NB)
        ((float*)ai_s)[tid] = ai[bf * NS * NB + tid];
    __syncthreads();
    if (tid < NB) {
        float a = 0.f;
        #pragma unroll
        for (int s = 0; s < NS; ++s) a += ai_s[s][tid];
        A_s[tid] = a;
    }
    __syncthreads();

    const float4* segp = (const float4*)(seg  + (size_t)bf * NB * HW)       + v4;
    const float4* mp   = (const float4*)(masks + (size_t)bf * NS * HW)      + v4;
    const float4* rp   = (const float4*)(rec  + (size_t)bf * NB * NCH * HW) + v4;
    const float4* tp   = (const float4*)(rtgt + (size_t)bf * NCH * HW)      + v4;
    const float4* vp   = (const float4*)(mvis + (size_t)bf * NS * HW)       + v4;

    // ---- Issue ALL 33 float4 loads up front; keep results live. ----
    float4 sv[4];
    #pragma unroll
    for (int c4 = 0; c4 < 4; ++c4) sv[c4] = segp[(c0 + c4) * HW4];

    float4 rr[4][NCH];
    #pragma unroll
    for (int c4 = 0; c4 < 4; ++c4)
        #pragma unroll
        for (int ch = 0; ch < NCH; ++ch)
            rr[c4][ch] = rp[((c0 + c4) * NCH + ch) * HW4];

    float4 mv[NS], vv[NS];
    #pragma unroll
    for (int s = 0; s < NS; ++s) mv[s] = mp[s * HW4];
    #pragma unroll
    for (int s = 0; s < NS; ++s) vv[s] = vp[s * HW4];

    float4 tv[NCH];
    #pragma unroll
    for (int ch = 0; ch < NCH; ++ch) tv[ch] = tp[ch * HW4];

    // ---- Compute ----
    float mb[NS][4], vb[NS][4];
    #pragma unroll
    for (int s = 0; s < NS; ++s) {
        const float* m4  = (const float*)&mv[s];
        const float* v4p = (const float*)&vv[s];
        #pragma unroll
        for (int j = 0; j < 4; ++j) {
            mb[s][j] = (m4[j]  > 0.5f) ? 1.f : 0.f;
            vb[s][j] = (v4p[j] > 0.5f) ? 1.f : 0.f;
        }
    }

    float acc = 0.f;
    #pragma unroll
    for (int c4 = 0; c4 < 4; ++c4) {
        const int c = c0 + c4;
        const float Ac = A_s[c];
        const float* sp  = (const float*)&sv[c4];
        const float* r0p = (const float*)&rr[c4][0];
        const float* r1p = (const float*)&rr[c4][1];
        const float* r2p = (const float*)&rr[c4][2];
        const float* t0p = (const float*)&tv[0];
        const float* t1p = (const float*)&tv[1];
        const float* t2p = (const float*)&tv[2];
        #pragma unroll
        for (int j = 0; j < 4; ++j) {
            float s  = sp[j];
            float lp = fmaxf(__logf(s), LOG_CLAMP);
            float l1 = fmaxf(__logf(1.0f - s), LOG_CLAMP);
            float d0 = r0p[j] - t0p[j];
            float d1 = r1p[j] - t1p[j];
            float d2 = r2p[j] - t2p[j];
            float D  = d0 * d0 + d1 * d1 + d2 * d2;
            float U = 0.f, V = 0.f;
            #pragma unroll
            for (int s7 = 0; s7 < NS; ++s7) {
                float a = ai_s[s7][c];
                U = fmaf(mb[s7][j], a, U);
                V = fmaf(vb[s7][j], a, V);
            }
            acc += -(Ac * l1 + U * (lp - l1)) * INV_HW + 0.1f * V * D;
        }
    }

    // wave reduce, cross-wave via LDS, one plain store per block (no atomics)
    #pragma unroll
    for (int off = 32; off; off >>= 1) acc += __shfl_down(acc, off, 64);
    __shared__ float wsum[BLOCK / 64];
    const int wid  = tid >> 6;
    const int lane = tid & 63;
    if (lane == 0) wsum[wid] = acc;
    __syncthreads();
    if (tid == 0)
        part[blockIdx.x] = wsum[0] + wsum[1] + wsum[2] + wsum[3];
}

__global__ __launch_bounds__(64)
void reduce_kernel(const float* __restrict__ part, float* __restrict__ out) {
    float a = 0.f;
    #pragma unroll
    for (int i = 0; i < NPART / 64; ++i)
        a += part[i * 64 + threadIdx.x];
    #pragma unroll
    for (int off = 32; off; off >>= 1) a += __shfl_down(a, off, 64);
    if (threadIdx.x == 0) out[0] = a * SCALE;
}

extern "C" void kernel_launch(void* const* d_in, const int* in_sizes, int n_in,
                              void* d_out, int out_size, void* d_ws, size_t ws_size,
                              hipStream_t stream) {
    const float* seg   = (const float*)d_in[0];  // (4,6,8,128,128)
    const float* masks = (const float*)d_in[1];  // (4,6,7,128,128)
    const float* rec   = (const float*)d_in[2];  // (4,6,8,3,128,128)
    const float* rtgt  = (const float*)d_in[3];  // (4,6,3,128,128)
    const float* mvis  = (const float*)d_in[4];  // (4,6,7,128,128)
    const float* ai    = (const float*)d_in[5];  // (4,6,7,8)
    float* out  = (float*)d_out;
    float* part = (float*)d_ws;                  // 768 floats, fully overwritten each call

    em_loss_kernel<<<NPART, BLOCK, 0, stream>>>(seg, masks, rec, rtgt, mvis, ai, part);
    reduce_kernel<<<1, 64, 0, stream>>>(part, out);
}